// Round 11
// baseline (240.343 us; speedup 1.0000x reference)
//
#include <hip/hip_runtime.h>

typedef unsigned short u16;
typedef float f32x4 __attribute__((ext_vector_type(4)));
typedef __bf16 bf16x8 __attribute__((ext_vector_type(8)));
typedef unsigned short us8 __attribute__((ext_vector_type(8)));
typedef __attribute__((address_space(3))) const char* lds3_t;

#define EPS_ 1e-6f

__device__ __forceinline__ u16 f2bf(float f) {
    unsigned u = __float_as_uint(f);
    u += 0x7FFFu + ((u >> 16) & 1u);   // round-to-nearest-even
    return (u16)(u >> 16);
}
__device__ __forceinline__ float bf2f(u16 h) {
    return __uint_as_float(((unsigned)h) << 16);
}
__device__ __forceinline__ void gload_lds16(const void* g, void* l) {
    __builtin_amdgcn_global_load_lds(
        (const __attribute__((address_space(1))) void*)g,
        (__attribute__((address_space(3))) void*)l, 16, 0, 0);
}

// ---------------- fp32 -> bf16 convert (vectorized) ----------------
__global__ __launch_bounds__(256) void f32_to_bf16_kernel(
    const float* __restrict__ src, u16* __restrict__ dst, int n4)
{
    int i = blockIdx.x * 256 + threadIdx.x;
    if (i >= n4) return;
    float4 f = ((const float4*)src)[i];
    ushort4 o;
    o.x = f2bf(f.x); o.y = f2bf(f.y); o.z = f2bf(f.z); o.w = f2bf(f.w);
    ((ushort4*)dst)[i] = o;
}

// ------- fused Wq|Wk|Wv convert + bias concat (single launch) -------
__global__ __launch_bounds__(256) void w_convert_fused(
    const float* __restrict__ Wq, const float* __restrict__ Wk,
    const float* __restrict__ Wv, const float* __restrict__ bq,
    const float* __restrict__ bk, const float* __restrict__ bv,
    u16* __restrict__ wqkvbf, float* __restrict__ bcat)
{
    int b = blockIdx.x;
    if (b < 3072) {
        const float* src = (b < 1024) ? Wq : ((b < 2048) ? Wk : Wv);
        int which = b >> 10, lb = b & 1023;
        int i = lb * 256 + threadIdx.x;
        float4 f = ((const float4*)src)[i];
        ushort4 o;
        o.x = f2bf(f.x); o.y = f2bf(f.y); o.z = f2bf(f.z); o.w = f2bf(f.w);
        ((ushort4*)(wqkvbf + (size_t)which * 1048576))[i] = o;
    } else {
        int which = b - 3072;
        const float* src = (which == 0) ? bq : ((which == 1) ? bk : bv);
        ((float4*)(bcat + which * 1024))[threadIdx.x] =
            ((const float4*)src)[threadIdx.x];
    }
}

// =================================================================
// 256x128 GEMM tile, BK=32, 4 waves (2M x 2N), per-wave 128x64 output.
// LDS: 3 rotating buffers x 24KB (A 16KB: 256 rows x 32k; B 8KB: 128 x 32k)
// = 72KB -> 2 independent blocks/CU (the r10 diagnosis: one 8-wave barrier
// group stalls the whole CU; two 4-wave blocks decorrelate barrier/vmcnt
// stalls so the other block's waves keep the matrix pipe fed [m114]).
// Swizzle: EXACT r8 formulas (only verified conflict-free pattern):
//   stage chunk c16: row=c16>>2, sl=c16&3, ksrc=kbase+((sl^((row>>1)&3))<<3)
//   read: off(r) = r*64 + ((g ^ ((i>>1)&3))<<4)
// Schedule/tile: VMCNT(6)+BARRIER -> stage t+2 (6 loads) -> 12 ds_reads ->
// LGKM(4) -> 16 MFMA -> LGKM(0) -> 16 MFMA.
// Hazards: VMCNT(6) at t drains tile t's 6 stages (leaves t+1's 6 in
// flight; vmcnt in-order). Barrier at t: every wave ran LGKM(0) in t-1 =>
// all t-1 reads retired => staging slot (t+2)%3 (= (t-1)%3) is dead.
// Stages at t target slot (t+2)%3, never the read slot t%3 (3 bufs).
// =================================================================

__device__ __forceinline__ void stage_a(
    const u16* __restrict__ src, int K, int kbase, char* slot, int tid)
{
    const int w = tid >> 6, l = tid & 63;
    #pragma unroll
    for (int j = 0; j < 4; ++j) {
        int c16 = j * 256 + w * 64 + l;       // 0..1023
        int row = c16 >> 2;                   // 0..255
        int sl  = c16 & 3;
        int ksrc = kbase + ((sl ^ ((row >> 1) & 3)) << 3);
        gload_lds16(src + (size_t)row * K + ksrc, slot + j * 4096 + w * 1024);
    }
}
__device__ __forceinline__ void stage_b(
    const u16* __restrict__ src, int K, int kbase, char* slot, int tid)
{
    const int w = tid >> 6, l = tid & 63;
    #pragma unroll
    for (int j = 0; j < 2; ++j) {
        int c16 = j * 256 + w * 64 + l;       // 0..511
        int row = c16 >> 2;                   // 0..127
        int sl  = c16 & 3;
        int ksrc = kbase + ((sl ^ ((row >> 1) & 3)) << 3);
        gload_lds16(src + (size_t)row * K + ksrc, slot + j * 4096 + w * 1024);
    }
}

#define BARRIER()  asm volatile("s_barrier" ::: "memory")
#define VMCNT6()   asm volatile("s_waitcnt vmcnt(6)" ::: "memory")
#define VMCNT0()   asm volatile("s_waitcnt vmcnt(0)" ::: "memory")

#define DSR_(dst_, base_, OFFSTR_) \
    asm volatile("ds_read_b128 %0, %1 offset:" OFFSTR_ \
                 : "=v"(dst_) : "v"((lds3_t)(base_)))
#define DSR(dst_, base_, OFF_) DSR_(dst_, base_, #OFF_)

#define LGKM_(NSTR_) asm volatile("s_waitcnt lgkmcnt(" NSTR_ ")" ::: "memory")
#define LGKM(N_) do { LGKM_(#N_); __builtin_amdgcn_sched_barrier(0); } while (0)

#define MFMA1(M_, N_, AF_, BF_) \
    acc[M_][N_] = __builtin_amdgcn_mfma_f32_16x16x32_bf16(BF_, AF_, acc[M_][N_], 0, 0, 0)

#define QUAD(M0, A0_, A1_, A2_, A3_, B0_, B1_, B2_, B3_) do { \
    __builtin_amdgcn_s_setprio(1); \
    MFMA1(M0+0, 0, A0_, B0_); MFMA1(M0+0, 1, A0_, B1_); MFMA1(M0+0, 2, A0_, B2_); MFMA1(M0+0, 3, A0_, B3_); \
    MFMA1(M0+1, 0, A1_, B0_); MFMA1(M0+1, 1, A1_, B1_); MFMA1(M0+1, 2, A1_, B2_); MFMA1(M0+1, 3, A1_, B3_); \
    MFMA1(M0+2, 0, A2_, B0_); MFMA1(M0+2, 1, A2_, B1_); MFMA1(M0+2, 2, A2_, B2_); MFMA1(M0+2, 3, A2_, B3_); \
    MFMA1(M0+3, 0, A3_, B0_); MFMA1(M0+3, 1, A3_, B1_); MFMA1(M0+3, 2, A3_, B2_); MFMA1(M0+3, 3, A3_, B3_); \
    __builtin_amdgcn_s_setprio(0); \
} while (0)

template<int MODE>
__global__ __launch_bounds__(256, 2) void gemm8p(
    const u16* __restrict__ A, const u16* __restrict__ B,
    const float* __restrict__ bias,
    u16* __restrict__ oq, u16* __restrict__ ok, u16* __restrict__ ov,
    float* __restrict__ outf, int M, int N, int K)
{
    extern __shared__ char lds[];
    const int tid  = threadIdx.x;
    const int lane = tid & 63;
    const int wv   = tid >> 6;         // 0..3
    const int wm   = wv >> 1;          // 0..1 : 128-row half
    const int wn   = wv & 1;           // 0..1 : 64-col half
    const int NT = K >> 5;             // BK=32

    // bijective XCD chunk swizzle (nwg % 8 == 0 for both grids)
    int bx, by;
    {
        const int gx = gridDim.x;
        int wg  = blockIdx.y * gx + blockIdx.x;
        int cpx = (gx * gridDim.y) >> 3;
        int swz = (wg & 7) * cpx + (wg >> 3);
        bx = swz % gx; by = swz / gx;
    }

    const u16* Ab = A + (size_t)by * 256 * K;
    const u16* Bb = B + (size_t)bx * 128 * K;

    const int i  = lane & 15, g = lane >> 4;
    const int fo = ((g ^ ((i >> 1) & 3)) << 4);
    const int aoff = (wm * 128 + i) * 64 + fo;
    const int boff = (wn * 64 + i) * 64 + fo;

    f32x4 acc[8][4];
    #pragma unroll
    for (int m = 0; m < 8; ++m)
        #pragma unroll
        for (int n = 0; n < 4; ++n) {
            acc[m][n][0] = 0.f; acc[m][n][1] = 0.f;
            acc[m][n][2] = 0.f; acc[m][n][3] = 0.f;
        }

    // slots s*24576: A @0 (16KB), B @16384 (8KB). Prologue: tiles 0,1.
    stage_a(Ab, K, 0,  lds + 0,             tid);
    stage_b(Bb, K, 0,  lds + 16384,         tid);
    stage_a(Ab, K, 32, lds + 24576,         tid);
    stage_b(Bb, K, 32, lds + 24576 + 16384, tid);

    for (int t = 0; t < NT; ++t) {
        char* cb = lds + (t % 3) * 24576;
        char* sb = lds + ((t + 2) % 3) * 24576;
        const int t2 = (t + 2 < NT) ? t + 2 : NT - 1;

        VMCNT6();            // tile t's 6 stages landed (t+1's stay in flight)
        BARRIER();           // all waves' t-1 reads retired (LGKM(0) in t-1)

        stage_a(Ab, K, t2 * 32, sb,         tid);   // tile t+2 -> dead slot
        stage_b(Bb, K, t2 * 32, sb + 16384, tid);

        const char* aB = cb + aoff;
        const char* bB = cb + 16384 + boff;
        bf16x8 a0, a1, a2, a3, a4, a5, a6, a7, b0, b1, b2, b3;

        DSR(b0, bB, 0); DSR(b1, bB, 1024); DSR(b2, bB, 2048); DSR(b3, bB, 3072);
        DSR(a0, aB, 0); DSR(a1, aB, 1024); DSR(a2, aB, 2048); DSR(a3, aB, 3072);
        DSR(a4, aB, 4096); DSR(a5, aB, 5120); DSR(a6, aB, 6144); DSR(a7, aB, 7168);

        LGKM(4);             // oldest 8 done: b0-3 + a0-3
        QUAD(0, a0, a1, a2, a3, b0, b1, b2, b3);
        LGKM(0);             // a4-7 done
        QUAD(4, a4, a5, a6, a7, b0, b1, b2, b3);
    }
    VMCNT0();   // drain tail stages before epilogue/endpgm

    // epilogue: lane holds row (i) x 4 consecutive cols (g*4..g*4+3)
    const int rowg0 = by * 256 + wm * 128;
    const int colg0 = bx * 128 + wn * 64;

    if (MODE == 1) {
        const int which = colg0 >> 10;               // uniform per block
        u16* dst = (which == 0) ? oq : ((which == 1) ? ok : ov);
        const bool dophi = (which < 2);
        const int cbo = colg0 & 1023;
        float4 bs[4];
        #pragma unroll
        for (int n = 0; n < 4; ++n)
            bs[n] = *(const float4*)(bias + colg0 + n * 16 + g * 4);
        #pragma unroll
        for (int m = 0; m < 8; ++m) {
            int row = rowg0 + m * 16 + i;
            #pragma unroll
            for (int n = 0; n < 4; ++n) {
                float v0 = acc[m][n][0] + bs[n].x;
                float v1 = acc[m][n][1] + bs[n].y;
                float v2 = acc[m][n][2] + bs[n].z;
                float v3 = acc[m][n][3] + bs[n].w;
                if (dophi) {
                    v0 = (v0 > 0.f) ? (v0 + 1.f) : __expf(v0);
                    v1 = (v1 > 0.f) ? (v1 + 1.f) : __expf(v1);
                    v2 = (v2 > 0.f) ? (v2 + 1.f) : __expf(v2);
                    v3 = (v3 > 0.f) ? (v3 + 1.f) : __expf(v3);
                }
                ushort4 o;
                o.x = f2bf(v0); o.y = f2bf(v1); o.z = f2bf(v2); o.w = f2bf(v3);
                *(ushort4*)(dst + (size_t)row * 1024 + cbo + n * 16 + g * 4) = o;
            }
        }
    } else {
        float4 bs[4];
        #pragma unroll
        for (int n = 0; n < 4; ++n)
            bs[n] = *(const float4*)(bias + colg0 + n * 16 + g * 4);
        #pragma unroll
        for (int m = 0; m < 8; ++m) {
            int row = rowg0 + m * 16 + i;
            #pragma unroll
            for (int n = 0; n < 4; ++n) {
                float4 o;
                o.x = acc[m][n][0] + bs[n].x;
                o.y = acc[m][n][1] + bs[n].y;
                o.z = acc[m][n][2] + bs[n].z;
                o.w = acc[m][n][3] + bs[n].w;
                *(float4*)(outf + (size_t)row * N + colg0 + n * 16 + g * 4) = o;
            }
        }
    }
}

// ---------------- kv partial: kv[b,h,d,m] = sum_s k*v ; ksum[b,h,d] = sum_s k -----
__global__ __launch_bounds__(256) void kv_partial(
    const u16* __restrict__ kbf, const u16* __restrict__ vbf,
    const float* __restrict__ mask, float* __restrict__ kvp, float* __restrict__ ksp)
{
    const int bh = blockIdx.x, ch = blockIdx.y;
    const int b = bh >> 4, h = bh & 15;
    const int tid = threadIdx.x;
    __shared__ __align__(16) float ks[32][64];
    __shared__ __align__(16) float vs[32][64];
    const int dg = tid >> 4, mg = tid & 15;
    float acc[4][4] = {};
    float ksa[4] = {};
    const int s0 = ch * 256;
    const int lr = tid >> 3, lc = (tid & 7) * 8;
    for (int sb = 0; sb < 256; sb += 32) {
        {
            size_t grow = (size_t)b * 4096 + (s0 + sb + lr);
            float mm = mask[grow];
            size_t off = (grow << 10) + (h << 6) + lc;
            us8 ku = __builtin_bit_cast(us8, *(const bf16x8*)(kbf + off));
            us8 vu = __builtin_bit_cast(us8, *(const bf16x8*)(vbf + off));
            float4 k0, k1, v0, v1;
            k0.x = bf2f(ku[0]) * mm; k0.y = bf2f(ku[1]) * mm;
            k0.z = bf2f(ku[2]) * mm; k0.w = bf2f(ku[3]) * mm;
            k1.x = bf2f(ku[4]) * mm; k1.y = bf2f(ku[5]) * mm;
            k1.z = bf2f(ku[6]) * mm; k1.w = bf2f(ku[7]) * mm;
            v0.x = bf2f(vu[0]) * mm; v0.y = bf2f(vu[1]) * mm;
            v0.z = bf2f(vu[2]) * mm; v0.w = bf2f(vu[3]) * mm;
            v1.x = bf2f(vu[4]) * mm; v1.y = bf2f(vu[5]) * mm;
            v1.z = bf2f(vu[6]) * mm; v1.w = bf2f(vu[7]) * mm;
            *(float4*)&ks[lr][lc]     = k0;
            *(float4*)&ks[lr][lc + 4] = k1;
            *(float4*)&vs[lr][lc]     = v0;
            *(float4*)&vs[lr][lc + 4] = v1;
        }
        __syncthreads();
        #pragma unroll
        for (int ss = 0; ss < 32; ++ss) {
            float4 k4 = *(const float4*)&ks[ss][dg << 2];
            float4 v4 = *(const float4*)&vs[ss][mg << 2];
            float ka[4] = {k4.x, k4.y, k4.z, k4.w};
            float va[4] = {v4.x, v4.y, v4.z, v4.w};
            #pragma unroll
            for (int di = 0; di < 4; ++di) {
                ksa[di] += ka[di];
                #pragma unroll
                for (int mi = 0; mi < 4; ++mi) acc[di][mi] += ka[di] * va[mi];
            }
        }
        __syncthreads();
    }
    float* o = kvp + (((size_t)ch * 64 + bh) << 12);
    #pragma unroll
    for (int di = 0; di < 4; ++di)
        #pragma unroll
        for (int mi = 0; mi < 4; ++mi)
            o[(dg * 4 + di) * 64 + (mg * 4 + mi)] = acc[di][mi];
    if (mg == 0) {
        float* os = ksp + (((size_t)ch * 64 + bh) << 6);
        #pragma unroll
        for (int di = 0; di < 4; ++di) os[dg * 4 + di] = ksa[di];
    }
}

// ---------------- reduce 16 partials -> kv^T (bf16) + ksum (bf16) ----------------
__global__ __launch_bounds__(256) void kv_reduce(
    const float* __restrict__ kvp, const float* __restrict__ ksp,
    u16* __restrict__ kvTbf, u16* __restrict__ ksumbf)
{
    const int bh = blockIdx.x, tid = threadIdx.x;
    for (int idx = tid; idx < 4096; idx += 256) {
        float s = 0.f;
        #pragma unroll
        for (int c = 0; c < 16; ++c) s += kvp[(((size_t)c * 64 + bh) << 12) + idx];
        int d = idx >> 6, m = idx & 63;
        kvTbf[((size_t)bh << 12) + (m << 6) + d] = f2bf(s);   // transposed: [m][d]
    }
    if (tid < 64) {
        float s = 0.f;
        #pragma unroll
        for (int c = 0; c < 16; ++c) s += ksp[(((size_t)c * 64 + bh) << 6) + tid];
        ksumbf[(bh << 6) + tid] = f2bf(s);
    }
}

// ---------------- attn: out[s,m] = (sum_d q[s,d] kv[d,m]) / (q . ksum + eps) ------
__global__ __launch_bounds__(256) void attn_kernel(
    const u16* __restrict__ qbf, const u16* __restrict__ kvTbf,
    const u16* __restrict__ ksumbf, u16* __restrict__ attnbf)
{
    const int bh = blockIdx.x;
    const int b = bh >> 4, h = bh & 15;
    const int tid = threadIdx.x, lane = tid & 63, wv = tid >> 6;
    __shared__ __align__(16) u16 kvs[64 * 64];
    __shared__ __align__(16) u16 kss[64];

    {
        const uint4* src = (const uint4*)(kvTbf + ((size_t)bh << 12));
        for (int u = tid; u < 512; u += 256) {
            uint4 d4 = src[u];
            int m = u >> 3, slot = u & 7;
            *(uint4*)((char*)kvs + m * 128 + ((slot ^ (m & 7)) << 4)) = d4;
        }
        if (tid < 32)
            ((unsigned*)kss)[tid] = ((const unsigned*)(ksumbf + ((size_t)bh << 6)))[tid];
    }
    __syncthreads();

    bf16x8 bfr[2][4], bnf[2];
    #pragma unroll
    for (int kk = 0; kk < 2; ++kk) {
        int kslot = kk * 4 + (lane >> 4);
        #pragma unroll
        for (int n = 0; n < 4; ++n) {
            int m = n * 16 + (lane & 15);
            bfr[kk][n] = *(const bf16x8*)((const char*)kvs + m * 128 +
                                          ((kslot ^ (m & 7)) << 4));
        }
        #pragma unroll
        for (int i2 = 0; i2 < 8; ++i2) bnf[kk][i2] = (__bf16)0.0f;
        if ((lane & 15) == 0)
            bnf[kk] = *(const bf16x8*)((const char*)kss + (kslot << 4));
    }

    const int sbase = blockIdx.y * 256 + wv * 16;
    for (int it = 0; it < 4; ++it) {
        const int st = sbase + it * 64;
        f32x4 acc[4], nacc;
        #pragma unroll
        for (int n = 0; n < 4; ++n) {
            acc[n][0] = 0.f; acc[n][1] = 0.f; acc[n][2] = 0.f; acc[n][3] = 0.f;
        }
        nacc[0] = 0.f; nacc[1] = 0.f; nacc[2] = 0.f; nacc[3] = 0.f;
        #pragma unroll
        for (int kk = 0; kk < 2; ++kk) {
            size_t goff = (((size_t)(b * 4096 + st + (lane & 15))) << 10) +
                          (h << 6) + kk * 32 + ((lane >> 4) << 3);
            bf16x8 af = *(const bf16x8*)(qbf + goff);
            #pragma unroll
            for (int n = 0; n < 4; ++n)
                acc[n] = __builtin_amdgcn_mfma_f32_16x16x32_bf16(af, bfr[kk][n], acc[n], 0, 0, 0);
            nacc = __builtin_amdgcn_mfma_f32_16x16x32_bf16(af, bnf[kk], nacc, 0, 0, 0);
        }
        float inv[4];
        #pragma unroll
        for (int j = 0; j < 4; ++j) {
            float nj = __shfl(nacc[j], lane & 48);
            inv[j] = 1.0f / (nj + EPS_);
        }
        #pragma unroll
        for (int n = 0; n < 4; ++n)
            #pragma unroll
            for (int j = 0; j < 4; ++j) {
                int row = st + ((lane >> 4) << 2) + j;
                attnbf[(((size_t)(b * 4096 + row)) << 10) + (h << 6) + n * 16 + (lane & 15)]
                    = f2bf(acc[n][j] * inv[j]);
            }
    }
}

extern "C" void kernel_launch(void* const* d_in, const int* in_sizes, int n_in,
                              void* d_out, int out_size, void* d_ws, size_t ws_size,
                              hipStream_t stream) {
    const float* x    = (const float*)d_in[0];
    const float* mask = (const float*)d_in[1];
    const float* Wq   = (const float*)d_in[2];
    const float* bq   = (const float*)d_in[3];
    const float* Wk   = (const float*)d_in[4];
    const float* bk   = (const float*)d_in[5];
    const float* Wv   = (const float*)d_in[6];
    const float* bv   = (const float*)d_in[7];
    const float* Wo   = (const float*)d_in[8];
    const float* bo   = (const float*)d_in[9];
    float* out = (float*)d_out;

    if (ws_size < 142606336u) return;  // need 136 MiB

    char* ws = (char*)d_ws;
    u16*   xbf    = (u16*)ws;                     // 32 MB, dead after qkv gemm
    u16*   wqkvbf = (u16*)(ws + 33554432);        // 6 MB (Wq|Wk|Wv rows)
    float* bcat   = (float*)(ws + 39845888);      // 12 KB (bq|bk|bv)
    u16*   qbf    = (u16*)(ws + 41943040);        // 32 MB
    u16*   kbf    = qbf + 16777216;               // 32 MB
    u16*   vbf    = kbf + 16777216;               // 32 MB
    u16*   attnbf = kbf;                          // reuse (k dead after kv_partial)
    float* kvp    = (float*)ws;                   // 16 MB (after xbf dead)
    float* ksp    = (float*)(ws + 16777216);      // 256 KB
    u16*   kvTbf  = (u16*)(ws + 17039360);        // 512 KB
    u16*   ksumbf = (u16*)(ws + 17563648);        // 8 KB
    u16*   wobf   = (u16*)(ws + 20971520);        // 2 MB

    f32_to_bf16_kernel<<<16384, 256, 0, stream>>>(x, xbf, 16777216 / 4);
    w_convert_fused<<<3075, 256, 0, stream>>>(Wq, Wk, Wv, bq, bk, bv, wqkvbf, bcat);

    // fused QKV projection: [16384,1024] @ [3072,1024]^T, phi on q,k
    gemm8p<1><<<dim3(24, 64), 256, 73728, stream>>>(
        xbf, wqkvbf, bcat, qbf, kbf, vbf, nullptr, 16384, 3072, 1024);

    f32_to_bf16_kernel<<<1024, 256, 0, stream>>>(Wo, wobf, 1048576 / 4);

    kv_partial<<<dim3(64, 16), 256, 0, stream>>>(kbf, vbf, mask, kvp, ksp);
    kv_reduce<<<64, 256, 0, stream>>>(kvp, ksp, kvTbf, ksumbf);

    attn_kernel<<<dim3(64, 16), 256, 0, stream>>>(qbf, kvTbf, ksumbf, attnbf);

    gemm8p<0><<<dim3(8, 64), 256, 73728, stream>>>(
        attnbf, wobf, bo, nullptr, nullptr, nullptr, out, 16384, 1024, 1024);
}

// Round 12
// 223.190 us; speedup vs baseline: 1.0769x; 1.0769x over previous
//
#include <hip/hip_runtime.h>

typedef unsigned short u16;
typedef float f32x4 __attribute__((ext_vector_type(4)));
typedef __bf16 bf16x8 __attribute__((ext_vector_type(8)));
typedef unsigned short us8 __attribute__((ext_vector_type(8)));
typedef __attribute__((address_space(3))) const char* lds3_t;

#define EPS_ 1e-6f

__device__ __forceinline__ u16 f2bf(float f) {
    unsigned u = __float_as_uint(f);
    u += 0x7FFFu + ((u >> 16) & 1u);   // round-to-nearest-even
    return (u16)(u >> 16);
}
__device__ __forceinline__ float bf2f(u16 h) {
    return __uint_as_float(((unsigned)h) << 16);
}
__device__ __forceinline__ void gload_lds16(const void* g, void* l) {
    __builtin_amdgcn_global_load_lds(
        (const __attribute__((address_space(1))) void*)g,
        (__attribute__((address_space(3))) void*)l, 16, 0, 0);
}

// ---------------- fp32 -> bf16 convert (vectorized) ----------------
__global__ __launch_bounds__(256) void f32_to_bf16_kernel(
    const float* __restrict__ src, u16* __restrict__ dst, int n4)
{
    int i = blockIdx.x * 256 + threadIdx.x;
    if (i >= n4) return;
    float4 f = ((const float4*)src)[i];
    ushort4 o;
    o.x = f2bf(f.x); o.y = f2bf(f.y); o.z = f2bf(f.z); o.w = f2bf(f.w);
    ((ushort4*)dst)[i] = o;
}

// ---- fused x + Wq|Wk|Wv convert + bias concat (single launch) ----
__global__ __launch_bounds__(256) void convert_all(
    const float* __restrict__ x,
    const float* __restrict__ Wq, const float* __restrict__ Wk,
    const float* __restrict__ Wv, const float* __restrict__ bq,
    const float* __restrict__ bk, const float* __restrict__ bv,
    u16* __restrict__ xbf, u16* __restrict__ wqkvbf, float* __restrict__ bcat)
{
    int b = blockIdx.x;
    if (b < 16384) {
        int i = b * 256 + threadIdx.x;            // float4 idx over x (16M elems)
        float4 f = ((const float4*)x)[i];
        ushort4 o;
        o.x = f2bf(f.x); o.y = f2bf(f.y); o.z = f2bf(f.z); o.w = f2bf(f.w);
        ((ushort4*)xbf)[i] = o;
    } else if (b < 19456) {
        int wb = b - 16384;
        const float* src = (wb < 1024) ? Wq : ((wb < 2048) ? Wk : Wv);
        int which = wb >> 10, lb = wb & 1023;
        int i = lb * 256 + threadIdx.x;
        float4 f = ((const float4*)src)[i];
        ushort4 o;
        o.x = f2bf(f.x); o.y = f2bf(f.y); o.z = f2bf(f.z); o.w = f2bf(f.w);
        ((ushort4*)(wqkvbf + (size_t)which * 1048576))[i] = o;
    } else {
        int which = b - 19456;
        const float* src = (which == 0) ? bq : ((which == 1) ? bk : bv);
        ((float4*)(bcat + which * 1024))[threadIdx.x] =
            ((const float4*)src)[threadIdx.x];
    }
}

// =================================================================
// 256x256 GEMM, BK=64 in two 32-k half-tile units (16KB: 256 rows x 64B).
// LDS swizzle: byte(r,g) = r*64 + ((g ^ ((r>>1)&3)) << 4) — the ONLY
// verified-conflict-free pattern on this HW (0 conflicts r4-r8/r10; both
// r2/r3 line-based variants and r9's 32x32 variant conflicted at exactly
// 4/read — HW grouping model incomplete, do not deviate).
// r8 ISA-interleave schedule: inline-asm ds_read_b128 (order pinned) +
// counted lgkmcnt + sched_barrier(0); counted vmcnt(4).
// Hazards: ENTRY vmcnt(4)+barrier retires cb's 8 staged loads (k0(t+1)'s
// 4 stay in flight); MID barrier after LGKM(12) => all k0 reads drained
// before k0(t+2) staging overwrites cb's k0 slots.
// Measured plateau: ~894 TF (MfmaUtil ~39%) — m97-class structure ceiling;
// 9 schedule variants (r2-r11) all land 115-134 us on the qkv shape.
// =================================================================

__device__ __forceinline__ void stage_half(
    const u16* __restrict__ src, int K, int kbase, char* slot, int tid)
{
    const int w = tid >> 6, l = tid & 63;
    #pragma unroll
    for (int j = 0; j < 2; ++j) {
        int c16 = j * 512 + w * 64 + l;       // 16B-chunk index 0..1023
        int row = c16 >> 2;                   // logical row 0..255
        int sl  = c16 & 3;
        int ksrc = kbase + ((sl ^ ((row >> 1) & 3)) << 3);
        gload_lds16(src + (size_t)row * K + ksrc, slot + j * 8192 + w * 1024);
    }
}

#define BARRIER()  asm volatile("s_barrier" ::: "memory")
#define VMCNT4()   asm volatile("s_waitcnt vmcnt(4)" ::: "memory")
#define VMCNT0()   asm volatile("s_waitcnt vmcnt(0)" ::: "memory")

#define DSR_(dst_, base_, OFFSTR_) \
    asm volatile("ds_read_b128 %0, %1 offset:" OFFSTR_ \
                 : "=v"(dst_) : "v"((lds3_t)(base_)))
#define DSR(dst_, base_, OFF_) DSR_(dst_, base_, #OFF_)

#define LGKM_(NSTR_) asm volatile("s_waitcnt lgkmcnt(" NSTR_ ")" ::: "memory")
#define LGKM(N_) do { LGKM_(#N_); __builtin_amdgcn_sched_barrier(0); } while (0)

#define MFMA1(M_, N_, AF_, BF_) \
    acc[M_][N_] = __builtin_amdgcn_mfma_f32_16x16x32_bf16(BF_, AF_, acc[M_][N_], 0, 0, 0)

// quadrant: 4 m-rows x 4 n-cols
#define QUAD(M0, A0_, A1_, A2_, A3_, B0_, B1_, B2_, B3_) do { \
    __builtin_amdgcn_s_setprio(1); \
    MFMA1(M0+0, 0, A0_, B0_); MFMA1(M0+0, 1, A0_, B1_); MFMA1(M0+0, 2, A0_, B2_); MFMA1(M0+0, 3, A0_, B3_); \
    MFMA1(M0+1, 0, A1_, B0_); MFMA1(M0+1, 1, A1_, B1_); MFMA1(M0+1, 2, A1_, B2_); MFMA1(M0+1, 3, A1_, B3_); \
    MFMA1(M0+2, 0, A2_, B0_); MFMA1(M0+2, 1, A2_, B1_); MFMA1(M0+2, 2, A2_, B2_); MFMA1(M0+2, 3, A2_, B3_); \
    MFMA1(M0+3, 0, A3_, B0_); MFMA1(M0+3, 1, A3_, B1_); MFMA1(M0+3, 2, A3_, B2_); MFMA1(M0+3, 3, A3_, B3_); \
    __builtin_amdgcn_s_setprio(0); \
} while (0)

template<int MODE>
__global__ __launch_bounds__(512, 2) void gemm8p(
    const u16* __restrict__ A, const u16* __restrict__ B,
    const float* __restrict__ bias,
    u16* __restrict__ oq, u16* __restrict__ ok, u16* __restrict__ ov,
    float* __restrict__ outf, int M, int N, int K)
{
    extern __shared__ char lds[];
    const int tid  = threadIdx.x;
    const int lane = tid & 63;
    const int wv   = tid >> 6;
    const int wm   = wv >> 2;          // 0..1 : 128-row half
    const int wn   = wv & 3;           // 0..3 : 64-col quarter
    const int NT = K >> 6;

    // bijective XCD chunk swizzle (nwg % 8 == 0 for both grids)
    int bx, by;
    {
        const int gx = gridDim.x;
        int wg  = blockIdx.y * gx + blockIdx.x;
        int cpx = (gx * gridDim.y) >> 3;
        int swz = (wg & 7) * cpx + (wg >> 3);
        bx = swz % gx; by = swz / gx;
    }

    const u16* Ab = A + (size_t)by * 256 * K;
    const u16* Bb = B + (size_t)bx * 256 * K;

    const int i  = lane & 15, g = lane >> 4;
    const int fo = ((g ^ ((i >> 1) & 3)) << 4);
    const int aoff = (wm * 128 + i) * 64 + fo;
    const int boff = (wn * 64 + i) * 64 + fo;

    f32x4 acc[8][4];
    #pragma unroll
    for (int m = 0; m < 8; ++m)
        #pragma unroll
        for (int n = 0; n < 4; ++n) {
            acc[m][n][0] = 0.f; acc[m][n][1] = 0.f;
            acc[m][n][2] = 0.f; acc[m][n][3] = 0.f;
        }

    // buffer b at b*65536: A_k0 @0, B_k0 @16384, A_k1 @32768, B_k1 @49152
    // prologue: k0(0), k1(0), k0(1) = 12 loads/thread
    stage_half(Ab, K, 0,  lds + 0,             tid);
    stage_half(Bb, K, 0,  lds + 16384,         tid);
    stage_half(Ab, K, 32, lds + 32768,         tid);
    stage_half(Bb, K, 32, lds + 49152,         tid);
    stage_half(Ab, K, 64, lds + 65536 + 0,     tid);
    stage_half(Bb, K, 64, lds + 65536 + 16384, tid);

    for (int t = 0; t < NT; ++t) {
        char* cb = lds + ((t & 1) << 16);
        char* nb = lds + (((t + 1) & 1) << 16);
        const int t1 = (t + 1 < NT) ? t + 1 : NT - 1;
        const int t2 = (t + 2 < NT) ? t + 2 : NT - 1;

        // ---- ENTRY: retire cb's 8 staged loads (k0(t+1)'s 4 stay in flight)
        VMCNT4();
        BARRIER();

        const char* aK0 = cb + aoff;
        const char* bK0 = cb + 16384 + boff;
        const char* aK1 = cb + 32768 + aoff;
        const char* bK1 = cb + 49152 + boff;

        bf16x8 aL0, aL1, aL2, aL3, aH0, aH1, aH2, aH3, b00, b01, b02, b03;
        bf16x8 cL0, cL1, cL2, cL3, cH0, cH1, cH2, cH3, b10, b11, b12, b13;

        // issue k0 reads (12): b0, aL, aH  (asm volatile => order pinned)
        DSR(b00, bK0, 0); DSR(b01, bK0, 1024); DSR(b02, bK0, 2048); DSR(b03, bK0, 3072);
        DSR(aL0, aK0, 0); DSR(aL1, aK0, 1024); DSR(aL2, aK0, 2048); DSR(aL3, aK0, 3072);
        DSR(aH0, aK0, 4096); DSR(aH1, aK0, 5120); DSR(aH2, aK0, 6144); DSR(aH3, aK0, 7168);

        // stage k1(t+1) -> nb (vmcnt ops; don't touch lgkm)
        stage_half(Ab, K, t1 * 64 + 32, nb + 32768, tid);
        stage_half(Bb, K, t1 * 64 + 32, nb + 49152, tid);

        LGKM(4);                 // b0 + aL complete (aH may be in flight)
        QUAD(0, aL0, aL1, aL2, aL3, b00, b01, b02, b03);   // m0-3 x k0

        // issue k1 reads (12): b1, cL, cH — overlap with Q1/Q2 MFMA
        DSR(b10, bK1, 0); DSR(b11, bK1, 1024); DSR(b12, bK1, 2048); DSR(b13, bK1, 3072);
        DSR(cL0, aK1, 0); DSR(cL1, aK1, 1024); DSR(cL2, aK1, 2048); DSR(cL3, aK1, 3072);
        DSR(cH0, aK1, 4096); DSR(cH1, aK1, 5120); DSR(cH2, aK1, 6144); DSR(cH3, aK1, 7168);

        LGKM(12);                // aH complete; only the 12 k1 reads remain
        QUAD(4, aH0, aH1, aH2, aH3, b00, b01, b02, b03);   // m4-7 x k0

        // ---- MID: every wave ran LGKM(12) above => all k0 reads drained
        BARRIER();
        stage_half(Ab, K, t2 * 64, cb + 0,     tid);       // k0(t+2)
        stage_half(Bb, K, t2 * 64, cb + 16384, tid);

        LGKM(4);                 // b1 + cL complete
        QUAD(0, cL0, cL1, cL2, cL3, b10, b11, b12, b13);   // m0-3 x k1
        LGKM(0);                 // cH complete
        QUAD(4, cH0, cH1, cH2, cH3, b10, b11, b12, b13);   // m4-7 x k1
        // next ENTRY barrier protects nb's k1 slots (readers drained at LGKM(0))
    }
    VMCNT0();   // drain tail stages before epilogue/endpgm

    // epilogue: lane holds row (i) x 4 consecutive cols (g*4..g*4+3)
    const int rowg0 = by * 256 + wm * 128;
    const int colg0 = bx * 256 + wn * 64;

    if (MODE == 1) {
        const int which = colg0 >> 10;               // uniform per wave
        u16* dst = (which == 0) ? oq : ((which == 1) ? ok : ov);
        const bool dophi = (which < 2);
        const int cbo = colg0 & 1023;
        float4 bs[4];
        #pragma unroll
        for (int n = 0; n < 4; ++n)
            bs[n] = *(const float4*)(bias + colg0 + n * 16 + g * 4);
        #pragma unroll
        for (int m = 0; m < 8; ++m) {
            int row = rowg0 + m * 16 + i;
            #pragma unroll
            for (int n = 0; n < 4; ++n) {
                float v0 = acc[m][n][0] + bs[n].x;
                float v1 = acc[m][n][1] + bs[n].y;
                float v2 = acc[m][n][2] + bs[n].z;
                float v3 = acc[m][n][3] + bs[n].w;
                if (dophi) {
                    v0 = (v0 > 0.f) ? (v0 + 1.f) : __expf(v0);
                    v1 = (v1 > 0.f) ? (v1 + 1.f) : __expf(v1);
                    v2 = (v2 > 0.f) ? (v2 + 1.f) : __expf(v2);
                    v3 = (v3 > 0.f) ? (v3 + 1.f) : __expf(v3);
                }
                ushort4 o;
                o.x = f2bf(v0); o.y = f2bf(v1); o.z = f2bf(v2); o.w = f2bf(v3);
                *(ushort4*)(dst + (size_t)row * 1024 + cbo + n * 16 + g * 4) = o;
            }
        }
    } else {
        float4 bs[4];
        #pragma unroll
        for (int n = 0; n < 4; ++n)
            bs[n] = *(const float4*)(bias + colg0 + n * 16 + g * 4);
        #pragma unroll
        for (int m = 0; m < 8; ++m) {
            int row = rowg0 + m * 16 + i;
            #pragma unroll
            for (int n = 0; n < 4; ++n) {
                float4 o;
                o.x = acc[m][n][0] + bs[n].x;
                o.y = acc[m][n][1] + bs[n].y;
                o.z = acc[m][n][2] + bs[n].z;
                o.w = acc[m][n][3] + bs[n].w;
                *(float4*)(outf + (size_t)row * N + colg0 + n * 16 + g * 4) = o;
            }
        }
    }
}

// ---------------- kv partial: kv[b,h,d,m] = sum_s k*v ; ksum[b,h,d] = sum_s k -----
__global__ __launch_bounds__(256) void kv_partial(
    const u16* __restrict__ kbf, const u16* __restrict__ vbf,
    const float* __restrict__ mask, float* __restrict__ kvp, float* __restrict__ ksp)
{
    const int bh = blockIdx.x, ch = blockIdx.y;
    const int b = bh >> 4, h = bh & 15;
    const int tid = threadIdx.x;
    __shared__ __align__(16) float ks[32][64];
    __shared__ __align__(16) float vs[32][64];
    const int dg = tid >> 4, mg = tid & 15;
    float acc[4][4] = {};
    float ksa[4] = {};
    const int s0 = ch * 256;
    const int lr = tid >> 3, lc = (tid & 7) * 8;
    for (int sb = 0; sb < 256; sb += 32) {
        {
            size_t grow = (size_t)b * 4096 + (s0 + sb + lr);
            float mm = mask[grow];
            size_t off = (grow << 10) + (h << 6) + lc;
            us8 ku = __builtin_bit_cast(us8, *(const bf16x8*)(kbf + off));
            us8 vu = __builtin_bit_cast(us8, *(const bf16x8*)(vbf + off));
            float4 k0, k1, v0, v1;
            k0.x = bf2f(ku[0]) * mm; k0.y = bf2f(ku[1]) * mm;
            k0.z = bf2f(ku[2]) * mm; k0.w = bf2f(ku[3]) * mm;
            k1.x = bf2f(ku[4]) * mm; k1.y = bf2f(ku[5]) * mm;
            k1.z = bf2f(ku[6]) * mm; k1.w = bf2f(ku[7]) * mm;
            v0.x = bf2f(vu[0]) * mm; v0.y = bf2f(vu[1]) * mm;
            v0.z = bf2f(vu[2]) * mm; v0.w = bf2f(vu[3]) * mm;
            v1.x = bf2f(vu[4]) * mm; v1.y = bf2f(vu[5]) * mm;
            v1.z = bf2f(vu[6]) * mm; v1.w = bf2f(vu[7]) * mm;
            *(float4*)&ks[lr][lc]     = k0;
            *(float4*)&ks[lr][lc + 4] = k1;
            *(float4*)&vs[lr][lc]     = v0;
            *(float4*)&vs[lr][lc + 4] = v1;
        }
        __syncthreads();
        #pragma unroll
        for (int ss = 0; ss < 32; ++ss) {
            float4 k4 = *(const float4*)&ks[ss][dg << 2];
            float4 v4 = *(const float4*)&vs[ss][mg << 2];
            float ka[4] = {k4.x, k4.y, k4.z, k4.w};
            float va[4] = {v4.x, v4.y, v4.z, v4.w};
            #pragma unroll
            for (int di = 0; di < 4; ++di) {
                ksa[di] += ka[di];
                #pragma unroll
                for (int mi = 0; mi < 4; ++mi) acc[di][mi] += ka[di] * va[mi];
            }
        }
        __syncthreads();
    }
    float* o = kvp + (((size_t)ch * 64 + bh) << 12);
    #pragma unroll
    for (int di = 0; di < 4; ++di)
        #pragma unroll
        for (int mi = 0; mi < 4; ++mi)
            o[(dg * 4 + di) * 64 + (mg * 4 + mi)] = acc[di][mi];
    if (mg == 0) {
        float* os = ksp + (((size_t)ch * 64 + bh) << 6);
        #pragma unroll
        for (int di = 0; di < 4; ++di) os[dg * 4 + di] = ksa[di];
    }
}

// ---------------- reduce 16 partials -> kv^T (bf16) + ksum (bf16) ----------------
__global__ __launch_bounds__(256) void kv_reduce(
    const float* __restrict__ kvp, const float* __restrict__ ksp,
    u16* __restrict__ kvTbf, u16* __restrict__ ksumbf)
{
    const int bh = blockIdx.x, tid = threadIdx.x;
    for (int idx = tid; idx < 4096; idx += 256) {
        float s = 0.f;
        #pragma unroll
        for (int c = 0; c < 16; ++c) s += kvp[(((size_t)c * 64 + bh) << 12) + idx];
        int d = idx >> 6, m = idx & 63;
        kvTbf[((size_t)bh << 12) + (m << 6) + d] = f2bf(s);   // transposed: [m][d]
    }
    if (tid < 64) {
        float s = 0.f;
        #pragma unroll
        for (int c = 0; c < 16; ++c) s += ksp[(((size_t)c * 64 + bh) << 6) + tid];
        ksumbf[(bh << 6) + tid] = f2bf(s);
    }
}

// ---------------- attn: out[s,m] = (sum_d q[s,d] kv[d,m]) / (q . ksum + eps) ------
__global__ __launch_bounds__(256) void attn_kernel(
    const u16* __restrict__ qbf, const u16* __restrict__ kvTbf,
    const u16* __restrict__ ksumbf, u16* __restrict__ attnbf)
{
    const int bh = blockIdx.x;
    const int b = bh >> 4, h = bh & 15;
    const int tid = threadIdx.x, lane = tid & 63, wv = tid >> 6;
    __shared__ __align__(16) u16 kvs[64 * 64];
    __shared__ __align__(16) u16 kss[64];

    {
        const uint4* src = (const uint4*)(kvTbf + ((size_t)bh << 12));
        for (int u = tid; u < 512; u += 256) {
            uint4 d4 = src[u];
            int m = u >> 3, slot = u & 7;
            *(uint4*)((char*)kvs + m * 128 + ((slot ^ (m & 7)) << 4)) = d4;
        }
        if (tid < 32)
            ((unsigned*)kss)[tid] = ((const unsigned*)(ksumbf + ((size_t)bh << 6)))[tid];
    }
    __syncthreads();

    bf16x8 bfr[2][4], bnf[2];
    #pragma unroll
    for (int kk = 0; kk < 2; ++kk) {
        int kslot = kk * 4 + (lane >> 4);
        #pragma unroll
        for (int n = 0; n < 4; ++n) {
            int m = n * 16 + (lane & 15);
            bfr[kk][n] = *(const bf16x8*)((const char*)kvs + m * 128 +
                                          ((kslot ^ (m & 7)) << 4));
        }
        #pragma unroll
        for (int i2 = 0; i2 < 8; ++i2) bnf[kk][i2] = (__bf16)0.0f;
        if ((lane & 15) == 0)
            bnf[kk] = *(const bf16x8*)((const char*)kss + (kslot << 4));
    }

    const int sbase = blockIdx.y * 256 + wv * 16;
    for (int it = 0; it < 4; ++it) {
        const int st = sbase + it * 64;
        f32x4 acc[4], nacc;
        #pragma unroll
        for (int n = 0; n < 4; ++n) {
            acc[n][0] = 0.f; acc[n][1] = 0.f; acc[n][2] = 0.f; acc[n][3] = 0.f;
        }
        nacc[0] = 0.f; nacc[1] = 0.f; nacc[2] = 0.f; nacc[3] = 0.f;
        #pragma unroll
        for (int kk = 0; kk < 2; ++kk) {
            size_t goff = (((size_t)(b * 4096 + st + (lane & 15))) << 10) +
                          (h << 6) + kk * 32 + ((lane >> 4) << 3);
            bf16x8 af = *(const bf16x8*)(qbf + goff);
            #pragma unroll
            for (int n = 0; n < 4; ++n)
                acc[n] = __builtin_amdgcn_mfma_f32_16x16x32_bf16(af, bfr[kk][n], acc[n], 0, 0, 0);
            nacc = __builtin_amdgcn_mfma_f32_16x16x32_bf16(af, bnf[kk], nacc, 0, 0, 0);
        }
        float inv[4];
        #pragma unroll
        for (int j = 0; j < 4; ++j) {
            float nj = __shfl(nacc[j], lane & 48);
            inv[j] = 1.0f / (nj + EPS_);
        }
        #pragma unroll
        for (int n = 0; n < 4; ++n)
            #pragma unroll
            for (int j = 0; j < 4; ++j) {
                int row = st + ((lane >> 4) << 2) + j;
                attnbf[(((size_t)(b * 4096 + row)) << 10) + (h << 6) + n * 16 + (lane & 15)]
                    = f2bf(acc[n][j] * inv[j]);
            }
    }
}

extern "C" void kernel_launch(void* const* d_in, const int* in_sizes, int n_in,
                              void* d_out, int out_size, void* d_ws, size_t ws_size,
                              hipStream_t stream) {
    const float* x    = (const float*)d_in[0];
    const float* mask = (const float*)d_in[1];
    const float* Wq   = (const float*)d_in[2];
    const float* bq   = (const float*)d_in[3];
    const float* Wk   = (const float*)d_in[4];
    const float* bk   = (const float*)d_in[5];
    const float* Wv   = (const float*)d_in[6];
    const float* bv   = (const float*)d_in[7];
    const float* Wo   = (const float*)d_in[8];
    const float* bo   = (const float*)d_in[9];
    float* out = (float*)d_out;

    if (ws_size < 142606336u) return;  // need 136 MiB

    char* ws = (char*)d_ws;
    u16*   xbf    = (u16*)ws;                     // 32 MB, dead after qkv gemm
    u16*   wqkvbf = (u16*)(ws + 33554432);        // 6 MB (Wq|Wk|Wv rows)
    float* bcat   = (float*)(ws + 39845888);      // 12 KB (bq|bk|bv)
    u16*   qbf    = (u16*)(ws + 41943040);        // 32 MB
    u16*   kbf    = qbf + 16777216;               // 32 MB
    u16*   vbf    = kbf + 16777216;               // 32 MB
    u16*   attnbf = kbf;                          // reuse (k dead after kv_partial)
    float* kvp    = (float*)ws;                   // 16 MB (after xbf dead)
    float* ksp    = (float*)(ws + 16777216);      // 256 KB
    u16*   kvTbf  = (u16*)(ws + 17039360);        // 512 KB
    u16*   ksumbf = (u16*)(ws + 17563648);        // 8 KB
    u16*   wobf   = (u16*)(ws + 20971520);        // 2 MB (converted after qkv gemm)

    convert_all<<<19459, 256, 0, stream>>>(x, Wq, Wk, Wv, bq, bk, bv,
                                           xbf, wqkvbf, bcat);

    // fused QKV projection: [16384,1024] @ [3072,1024]^T, phi on q,k
    gemm8p<1><<<dim3(12, 64), 512, 131072, stream>>>(
        xbf, wqkvbf, bcat, qbf, kbf, vbf, nullptr, 16384, 3072, 1024);

    f32_to_bf16_kernel<<<1024, 256, 0, stream>>>(Wo, wobf, 1048576 / 4);

    kv_partial<<<dim3(64, 16), 256, 0, stream>>>(kbf, vbf, mask, kvp, ksp);
    kv_reduce<<<64, 256, 0, stream>>>(kvp, ksp, kvTbf, ksumbf);

    attn_kernel<<<dim3(64, 16), 256, 0, stream>>>(qbf, kvTbf, ksumbf, attnbf);

    gemm8p<0><<<dim3(4, 64), 512, 131072, stream>>>(
        attnbf, wobf, bo, nullptr, nullptr, nullptr, out, 16384, 1024, 1024);
}

// Round 13
// 221.454 us; speedup vs baseline: 1.0853x; 1.0078x over previous
//
#include <hip/hip_runtime.h>

typedef unsigned short u16;
typedef float f32x4 __attribute__((ext_vector_type(4)));
typedef __bf16 bf16x8 __attribute__((ext_vector_type(8)));
typedef unsigned short us8 __attribute__((ext_vector_type(8)));
typedef __attribute__((address_space(3))) const char* lds3_t;

#define EPS_ 1e-6f

__device__ __forceinline__ u16 f2bf(float f) {
    unsigned u = __float_as_uint(f);
    u += 0x7FFFu + ((u >> 16) & 1u);   // round-to-nearest-even
    return (u16)(u >> 16);
}
__device__ __forceinline__ float bf2f(u16 h) {
    return __uint_as_float(((unsigned)h) << 16);
}
__device__ __forceinline__ void gload_lds16(const void* g, void* l) {
    __builtin_amdgcn_global_load_lds(
        (const __attribute__((address_space(1))) void*)g,
        (__attribute__((address_space(3))) void*)l, 16, 0, 0);
}

// ---- fused x + Wq|Wk|Wv|Wo convert (single launch, grid 20480) ----
__global__ __launch_bounds__(256) void convert_all(
    const float* __restrict__ x,
    const float* __restrict__ Wq, const float* __restrict__ Wk,
    const float* __restrict__ Wv, const float* __restrict__ Wo,
    u16* __restrict__ xbf, u16* __restrict__ wqkvbf, u16* __restrict__ wobf)
{
    int b = blockIdx.x;
    const float* src;
    u16* dst;
    int i;
    if (b < 16384) {
        src = x; dst = xbf; i = b * 256 + threadIdx.x;
    } else {
        int wb = b - 16384;                 // 0..4095
        int which = wb >> 10;
        src = (which == 0) ? Wq : ((which == 1) ? Wk : ((which == 2) ? Wv : Wo));
        dst = (which < 3) ? (wqkvbf + (size_t)which * 1048576) : wobf;
        i = (wb & 1023) * 256 + threadIdx.x;
    }
    float4 f = ((const float4*)src)[i];
    ushort4 o;
    o.x = f2bf(f.x); o.y = f2bf(f.y); o.z = f2bf(f.z); o.w = f2bf(f.w);
    ((ushort4*)dst)[i] = o;
}

// =================================================================
// 256x256 GEMM, BK=64 in two 32-k half-tile units (16KB: 256 rows x 64B).
// LDS swizzle: byte(r,g) = r*64 + ((g ^ ((r>>1)&3)) << 4) — the ONLY
// verified-conflict-free pattern on this HW (0 conflicts r4-r12; r2/r3
// line-based and r9 32x32 variants all conflicted at exactly 4/read —
// HW grouping model incomplete, do not deviate).
// r8 ISA-interleave schedule: inline-asm ds_read_b128 (order pinned) +
// counted lgkmcnt + sched_barrier(0); counted vmcnt(4).
// Hazards: ENTRY vmcnt(4)+barrier retires cb's 8 staged loads (k0(t+1)'s
// 4 stay in flight); MID barrier after LGKM(12) => all k0 reads drained
// before k0(t+2) staging overwrites cb's k0 slots.
// Measured plateau: ~894 TF (MfmaUtil ~40%) — m97-class structure ceiling;
// 9 schedule variants (r2-r11) all land 115-134 us on the qkv shape.
// =================================================================

__device__ __forceinline__ void stage_half(
    const u16* __restrict__ src, int K, int kbase, char* slot, int tid)
{
    const int w = tid >> 6, l = tid & 63;
    #pragma unroll
    for (int j = 0; j < 2; ++j) {
        int c16 = j * 512 + w * 64 + l;       // 16B-chunk index 0..1023
        int row = c16 >> 2;                   // logical row 0..255
        int sl  = c16 & 3;
        int ksrc = kbase + ((sl ^ ((row >> 1) & 3)) << 3);
        gload_lds16(src + (size_t)row * K + ksrc, slot + j * 8192 + w * 1024);
    }
}

#define BARRIER()  asm volatile("s_barrier" ::: "memory")
#define VMCNT4()   asm volatile("s_waitcnt vmcnt(4)" ::: "memory")
#define VMCNT0()   asm volatile("s_waitcnt vmcnt(0)" ::: "memory")

#define DSR_(dst_, base_, OFFSTR_) \
    asm volatile("ds_read_b128 %0, %1 offset:" OFFSTR_ \
                 : "=v"(dst_) : "v"((lds3_t)(base_)))
#define DSR(dst_, base_, OFF_) DSR_(dst_, base_, #OFF_)

#define LGKM_(NSTR_) asm volatile("s_waitcnt lgkmcnt(" NSTR_ ")" ::: "memory")
#define LGKM(N_) do { LGKM_(#N_); __builtin_amdgcn_sched_barrier(0); } while (0)

#define MFMA1(M_, N_, AF_, BF_) \
    acc[M_][N_] = __builtin_amdgcn_mfma_f32_16x16x32_bf16(BF_, AF_, acc[M_][N_], 0, 0, 0)

// quadrant: 4 m-rows x 4 n-cols
#define QUAD(M0, A0_, A1_, A2_, A3_, B0_, B1_, B2_, B3_) do { \
    __builtin_amdgcn_s_setprio(1); \
    MFMA1(M0+0, 0, A0_, B0_); MFMA1(M0+0, 1, A0_, B1_); MFMA1(M0+0, 2, A0_, B2_); MFMA1(M0+0, 3, A0_, B3_); \
    MFMA1(M0+1, 0, A1_, B0_); MFMA1(M0+1, 1, A1_, B1_); MFMA1(M0+1, 2, A1_, B2_); MFMA1(M0+1, 3, A1_, B3_); \
    MFMA1(M0+2, 0, A2_, B0_); MFMA1(M0+2, 1, A2_, B1_); MFMA1(M0+2, 2, A2_, B2_); MFMA1(M0+2, 3, A2_, B3_); \
    MFMA1(M0+3, 0, A3_, B0_); MFMA1(M0+3, 1, A3_, B1_); MFMA1(M0+3, 2, A3_, B2_); MFMA1(M0+3, 3, A3_, B3_); \
    __builtin_amdgcn_s_setprio(0); \
} while (0)

template<int MODE>
__global__ __launch_bounds__(512, 2) void gemm8p(
    const u16* __restrict__ A, const u16* __restrict__ B,
    const float* __restrict__ b0p, const float* __restrict__ b1p,
    const float* __restrict__ b2p,
    u16* __restrict__ oq, u16* __restrict__ ok, u16* __restrict__ ov,
    float* __restrict__ outf, int M, int N, int K)
{
    extern __shared__ char lds[];
    const int tid  = threadIdx.x;
    const int lane = tid & 63;
    const int wv   = tid >> 6;
    const int wm   = wv >> 2;          // 0..1 : 128-row half
    const int wn   = wv & 3;           // 0..3 : 64-col quarter
    const int NT = K >> 6;

    // bijective XCD chunk swizzle (nwg % 8 == 0 for both grids)
    int bx, by;
    {
        const int gx = gridDim.x;
        int wg  = blockIdx.y * gx + blockIdx.x;
        int cpx = (gx * gridDim.y) >> 3;
        int swz = (wg & 7) * cpx + (wg >> 3);
        bx = swz % gx; by = swz / gx;
    }

    const u16* Ab = A + (size_t)by * 256 * K;
    const u16* Bb = B + (size_t)bx * 256 * K;

    const int i  = lane & 15, g = lane >> 4;
    const int fo = ((g ^ ((i >> 1) & 3)) << 4);
    const int aoff = (wm * 128 + i) * 64 + fo;
    const int boff = (wn * 64 + i) * 64 + fo;

    f32x4 acc[8][4];
    #pragma unroll
    for (int m = 0; m < 8; ++m)
        #pragma unroll
        for (int n = 0; n < 4; ++n) {
            acc[m][n][0] = 0.f; acc[m][n][1] = 0.f;
            acc[m][n][2] = 0.f; acc[m][n][3] = 0.f;
        }

    // buffer b at b*65536: A_k0 @0, B_k0 @16384, A_k1 @32768, B_k1 @49152
    // prologue: k0(0), k1(0), k0(1) = 12 loads/thread
    stage_half(Ab, K, 0,  lds + 0,             tid);
    stage_half(Bb, K, 0,  lds + 16384,         tid);
    stage_half(Ab, K, 32, lds + 32768,         tid);
    stage_half(Bb, K, 32, lds + 49152,         tid);
    stage_half(Ab, K, 64, lds + 65536 + 0,     tid);
    stage_half(Bb, K, 64, lds + 65536 + 16384, tid);

    for (int t = 0; t < NT; ++t) {
        char* cb = lds + ((t & 1) << 16);
        char* nb = lds + (((t + 1) & 1) << 16);
        const int t1 = (t + 1 < NT) ? t + 1 : NT - 1;
        const int t2 = (t + 2 < NT) ? t + 2 : NT - 1;

        // ---- ENTRY: retire cb's 8 staged loads (k0(t+1)'s 4 stay in flight)
        VMCNT4();
        BARRIER();

        const char* aK0 = cb + aoff;
        const char* bK0 = cb + 16384 + boff;
        const char* aK1 = cb + 32768 + aoff;
        const char* bK1 = cb + 49152 + boff;

        bf16x8 aL0, aL1, aL2, aL3, aH0, aH1, aH2, aH3, b00, b01, b02, b03;
        bf16x8 cL0, cL1, cL2, cL3, cH0, cH1, cH2, cH3, b10, b11, b12, b13;

        // issue k0 reads (12): b0, aL, aH  (asm volatile => order pinned)
        DSR(b00, bK0, 0); DSR(b01, bK0, 1024); DSR(b02, bK0, 2048); DSR(b03, bK0, 3072);
        DSR(aL0, aK0, 0); DSR(aL1, aK0, 1024); DSR(aL2, aK0, 2048); DSR(aL3, aK0, 3072);
        DSR(aH0, aK0, 4096); DSR(aH1, aK0, 5120); DSR(aH2, aK0, 6144); DSR(aH3, aK0, 7168);

        // stage k1(t+1) -> nb (vmcnt ops; don't touch lgkm)
        stage_half(Ab, K, t1 * 64 + 32, nb + 32768, tid);
        stage_half(Bb, K, t1 * 64 + 32, nb + 49152, tid);

        LGKM(4);                 // b0 + aL complete (aH may be in flight)
        QUAD(0, aL0, aL1, aL2, aL3, b00, b01, b02, b03);   // m0-3 x k0

        // issue k1 reads (12): b1, cL, cH — overlap with Q1/Q2 MFMA
        DSR(b10, bK1, 0); DSR(b11, bK1, 1024); DSR(b12, bK1, 2048); DSR(b13, bK1, 3072);
        DSR(cL0, aK1, 0); DSR(cL1, aK1, 1024); DSR(cL2, aK1, 2048); DSR(cL3, aK1, 3072);
        DSR(cH0, aK1, 4096); DSR(cH1, aK1, 5120); DSR(cH2, aK1, 6144); DSR(cH3, aK1, 7168);

        LGKM(12);                // aH complete; only the 12 k1 reads remain
        QUAD(4, aH0, aH1, aH2, aH3, b00, b01, b02, b03);   // m4-7 x k0

        // ---- MID: every wave ran LGKM(12) above => all k0 reads drained
        BARRIER();
        stage_half(Ab, K, t2 * 64, cb + 0,     tid);       // k0(t+2)
        stage_half(Bb, K, t2 * 64, cb + 16384, tid);

        LGKM(4);                 // b1 + cL complete
        QUAD(0, cL0, cL1, cL2, cL3, b10, b11, b12, b13);   // m0-3 x k1
        LGKM(0);                 // cH complete
        QUAD(4, cH0, cH1, cH2, cH3, b10, b11, b12, b13);   // m4-7 x k1
        // next ENTRY barrier protects nb's k1 slots (readers drained at LGKM(0))
    }
    VMCNT0();   // drain tail stages before epilogue/endpgm

    // epilogue: lane holds row (i) x 4 consecutive cols (g*4..g*4+3)
    const int rowg0 = by * 256 + wm * 128;
    const int colg0 = bx * 256 + wn * 64;

    if (MODE == 1) {
        const int which = colg0 >> 10;               // uniform per wave
        u16* dst = (which == 0) ? oq : ((which == 1) ? ok : ov);
        const float* bp = (which == 0) ? b0p : ((which == 1) ? b1p : b2p);
        const bool dophi = (which < 2);
        const int cbo = colg0 & 1023;
        float4 bs[4];
        #pragma unroll
        for (int n = 0; n < 4; ++n)
            bs[n] = *(const float4*)(bp + cbo + n * 16 + g * 4);
        #pragma unroll
        for (int m = 0; m < 8; ++m) {
            int row = rowg0 + m * 16 + i;
            #pragma unroll
            for (int n = 0; n < 4; ++n) {
                float v0 = acc[m][n][0] + bs[n].x;
                float v1 = acc[m][n][1] + bs[n].y;
                float v2 = acc[m][n][2] + bs[n].z;
                float v3 = acc[m][n][3] + bs[n].w;
                if (dophi) {
                    v0 = (v0 > 0.f) ? (v0 + 1.f) : __expf(v0);
                    v1 = (v1 > 0.f) ? (v1 + 1.f) : __expf(v1);
                    v2 = (v2 > 0.f) ? (v2 + 1.f) : __expf(v2);
                    v3 = (v3 > 0.f) ? (v3 + 1.f) : __expf(v3);
                }
                ushort4 o;
                o.x = f2bf(v0); o.y = f2bf(v1); o.z = f2bf(v2); o.w = f2bf(v3);
                *(ushort4*)(dst + (size_t)row * 1024 + cbo + n * 16 + g * 4) = o;
            }
        }
    } else {
        float4 bs[4];
        #pragma unroll
        for (int n = 0; n < 4; ++n)
            bs[n] = *(const float4*)(b0p + colg0 + n * 16 + g * 4);
        #pragma unroll
        for (int m = 0; m < 8; ++m) {
            int row = rowg0 + m * 16 + i;
            #pragma unroll
            for (int n = 0; n < 4; ++n) {
                float4 o;
                o.x = acc[m][n][0] + bs[n].x;
                o.y = acc[m][n][1] + bs[n].y;
                o.z = acc[m][n][2] + bs[n].z;
                o.w = acc[m][n][3] + bs[n].w;
                *(float4*)(outf + (size_t)row * N + colg0 + n * 16 + g * 4) = o;
            }
        }
    }
}

// ---------------- kv partial: kv[b,h,d,m] = sum_s k*v ; ksum[b,h,d] = sum_s k -----
__global__ __launch_bounds__(256) void kv_partial(
    const u16* __restrict__ kbf, const u16* __restrict__ vbf,
    const float* __restrict__ mask, float* __restrict__ kvp, float* __restrict__ ksp)
{
    const int bh = blockIdx.x, ch = blockIdx.y;
    const int b = bh >> 4, h = bh & 15;
    const int tid = threadIdx.x;
    __shared__ __align__(16) float ks[32][64];
    __shared__ __align__(16) float vs[32][64];
    const int dg = tid >> 4, mg = tid & 15;
    float acc[4][4] = {};
    float ksa[4] = {};
    const int s0 = ch * 256;
    const int lr = tid >> 3, lc = (tid & 7) * 8;
    for (int sb = 0; sb < 256; sb += 32) {
        {
            size_t grow = (size_t)b * 4096 + (s0 + sb + lr);
            float mm = mask[grow];
            size_t off = (grow << 10) + (h << 6) + lc;
            us8 ku = __builtin_bit_cast(us8, *(const bf16x8*)(kbf + off));
            us8 vu = __builtin_bit_cast(us8, *(const bf16x8*)(vbf + off));
            float4 k0, k1, v0, v1;
            k0.x = bf2f(ku[0]) * mm; k0.y = bf2f(ku[1]) * mm;
            k0.z = bf2f(ku[2]) * mm; k0.w = bf2f(ku[3]) * mm;
            k1.x = bf2f(ku[4]) * mm; k1.y = bf2f(ku[5]) * mm;
            k1.z = bf2f(ku[6]) * mm; k1.w = bf2f(ku[7]) * mm;
            v0.x = bf2f(vu[0]) * mm; v0.y = bf2f(vu[1]) * mm;
            v0.z = bf2f(vu[2]) * mm; v0.w = bf2f(vu[3]) * mm;
            v1.x = bf2f(vu[4]) * mm; v1.y = bf2f(vu[5]) * mm;
            v1.z = bf2f(vu[6]) * mm; v1.w = bf2f(vu[7]) * mm;
            *(float4*)&ks[lr][lc]     = k0;
            *(float4*)&ks[lr][lc + 4] = k1;
            *(float4*)&vs[lr][lc]     = v0;
            *(float4*)&vs[lr][lc + 4] = v1;
        }
        __syncthreads();
        #pragma unroll
        for (int ss = 0; ss < 32; ++ss) {
            float4 k4 = *(const float4*)&ks[ss][dg << 2];
            float4 v4 = *(const float4*)&vs[ss][mg << 2];
            float ka[4] = {k4.x, k4.y, k4.z, k4.w};
            float va[4] = {v4.x, v4.y, v4.z, v4.w};
            #pragma unroll
            for (int di = 0; di < 4; ++di) {
                ksa[di] += ka[di];
                #pragma unroll
                for (int mi = 0; mi < 4; ++mi) acc[di][mi] += ka[di] * va[mi];
            }
        }
        __syncthreads();
    }
    float* o = kvp + (((size_t)ch * 64 + bh) << 12);
    #pragma unroll
    for (int di = 0; di < 4; ++di)
        #pragma unroll
        for (int mi = 0; mi < 4; ++mi)
            o[(dg * 4 + di) * 64 + (mg * 4 + mi)] = acc[di][mi];
    if (mg == 0) {
        float* os = ksp + (((size_t)ch * 64 + bh) << 6);
        #pragma unroll
        for (int di = 0; di < 4; ++di) os[dg * 4 + di] = ksa[di];
    }
}

// ---------------- reduce 16 partials -> kv^T (bf16) + ksum (bf16) ----------------
__global__ __launch_bounds__(256) void kv_reduce(
    const float* __restrict__ kvp, const float* __restrict__ ksp,
    u16* __restrict__ kvTbf, u16* __restrict__ ksumbf)
{
    const int bh = blockIdx.x, tid = threadIdx.x;
    for (int idx = tid; idx < 4096; idx += 256) {
        float s = 0.f;
        #pragma unroll
        for (int c = 0; c < 16; ++c) s += kvp[(((size_t)c * 64 + bh) << 12) + idx];
        int d = idx >> 6, m = idx & 63;
        kvTbf[((size_t)bh << 12) + (m << 6) + d] = f2bf(s);   // transposed: [m][d]
    }
    if (tid < 64) {
        float s = 0.f;
        #pragma unroll
        for (int c = 0; c < 16; ++c) s += ksp[(((size_t)c * 64 + bh) << 6) + tid];
        ksumbf[(bh << 6) + tid] = f2bf(s);
    }
}

// ---------------- attn: out[s,m] = (sum_d q[s,d] kv[d,m]) / (q . ksum + eps) ------
__global__ __launch_bounds__(256) void attn_kernel(
    const u16* __restrict__ qbf, const u16* __restrict__ kvTbf,
    const u16* __restrict__ ksumbf, u16* __restrict__ attnbf)
{
    const int bh = blockIdx.x;
    const int b = bh >> 4, h = bh & 15;
    const int tid = threadIdx.x, lane = tid & 63, wv = tid >> 6;
    __shared__ __align__(16) u16 kvs[64 * 64];
    __shared__ __align__(16) u16 kss[64];

    {
        const uint4* src = (const uint4*)(kvTbf + ((size_t)bh << 12));
        for (int u = tid; u < 512; u += 256) {
            uint4 d4 = src[u];
            int m = u >> 3, slot = u & 7;
            *(uint4*)((char*)kvs + m * 128 + ((slot ^ (m & 7)) << 4)) = d4;
        }
        if (tid < 32)
            ((unsigned*)kss)[tid] = ((const unsigned*)(ksumbf + ((size_t)bh << 6)))[tid];
    }
    __syncthreads();

    bf16x8 bfr[2][4], bnf[2];
    #pragma unroll
    for (int kk = 0; kk < 2; ++kk) {
        int kslot = kk * 4 + (lane >> 4);
        #pragma unroll
        for (int n = 0; n < 4; ++n) {
            int m = n * 16 + (lane & 15);
            bfr[kk][n] = *(const bf16x8*)((const char*)kvs + m * 128 +
                                          ((kslot ^ (m & 7)) << 4));
        }
        #pragma unroll
        for (int i2 = 0; i2 < 8; ++i2) bnf[kk][i2] = (__bf16)0.0f;
        if ((lane & 15) == 0)
            bnf[kk] = *(const bf16x8*)((const char*)kss + (kslot << 4));
    }

    const int sbase = blockIdx.y * 256 + wv * 16;
    const size_t base0 = (((size_t)(b * 4096 + (lane & 15))) << 10) +
                         (h << 6) + ((lane >> 4) << 3);

    // software-prefetch q for next iteration (hide L2/HBM latency under MFMA)
    bf16x8 qa = *(const bf16x8*)(qbf + base0 + ((size_t)sbase << 10));
    bf16x8 qb = *(const bf16x8*)(qbf + base0 + ((size_t)sbase << 10) + 32);

    for (int it = 0; it < 4; ++it) {
        const int st  = sbase + it * 64;
        const int stn = sbase + ((it + 1 < 4) ? (it + 1) : 3) * 64;
        bf16x8 qan = *(const bf16x8*)(qbf + base0 + ((size_t)stn << 10));
        bf16x8 qbn = *(const bf16x8*)(qbf + base0 + ((size_t)stn << 10) + 32);

        f32x4 acc[4], nacc;
        #pragma unroll
        for (int n = 0; n < 4; ++n) {
            acc[n][0] = 0.f; acc[n][1] = 0.f; acc[n][2] = 0.f; acc[n][3] = 0.f;
        }
        nacc[0] = 0.f; nacc[1] = 0.f; nacc[2] = 0.f; nacc[3] = 0.f;

        #pragma unroll
        for (int n = 0; n < 4; ++n)
            acc[n] = __builtin_amdgcn_mfma_f32_16x16x32_bf16(qa, bfr[0][n], acc[n], 0, 0, 0);
        nacc = __builtin_amdgcn_mfma_f32_16x16x32_bf16(qa, bnf[0], nacc, 0, 0, 0);
        #pragma unroll
        for (int n = 0; n < 4; ++n)
            acc[n] = __builtin_amdgcn_mfma_f32_16x16x32_bf16(qb, bfr[1][n], acc[n], 0, 0, 0);
        nacc = __builtin_amdgcn_mfma_f32_16x16x32_bf16(qb, bnf[1], nacc, 0, 0, 0);

        float inv[4];
        #pragma unroll
        for (int j = 0; j < 4; ++j) {
            float nj = __shfl(nacc[j], lane & 48);
            inv[j] = 1.0f / (nj + EPS_);
        }
        #pragma unroll
        for (int n = 0; n < 4; ++n)
            #pragma unroll
            for (int j = 0; j < 4; ++j) {
                int row = st + ((lane >> 4) << 2) + j;
                attnbf[(((size_t)(b * 4096 + row)) << 10) + (h << 6) + n * 16 + (lane & 15)]
                    = f2bf(acc[n][j] * inv[j]);
            }
        qa = qan; qb = qbn;
    }
}

extern "C" void kernel_launch(void* const* d_in, const int* in_sizes, int n_in,
                              void* d_out, int out_size, void* d_ws, size_t ws_size,
                              hipStream_t stream) {
    const float* x    = (const float*)d_in[0];
    const float* mask = (const float*)d_in[1];
    const float* Wq   = (const float*)d_in[2];
    const float* bq   = (const float*)d_in[3];
    const float* Wk   = (const float*)d_in[4];
    const float* bk   = (const float*)d_in[5];
    const float* Wv   = (const float*)d_in[6];
    const float* bv   = (const float*)d_in[7];
    const float* Wo   = (const float*)d_in[8];
    const float* bo   = (const float*)d_in[9];
    float* out = (float*)d_out;

    if (ws_size < 142606336u) return;  // need 136 MiB

    char* ws = (char*)d_ws;
    u16*   xbf    = (u16*)ws;                     // 32 MB, dead after qkv gemm
    u16*   wqkvbf = (u16*)(ws + 33554432);        // 6 MB (Wq|Wk|Wv rows)
    u16*   wobf   = (u16*)(ws + 39845888);        // 2 MB (flush against qbf)
    u16*   qbf    = (u16*)(ws + 41943040);        // 32 MB
    u16*   kbf    = qbf + 16777216;               // 32 MB
    u16*   vbf    = kbf + 16777216;               // 32 MB
    u16*   attnbf = kbf;                          // reuse (k dead after kv_partial)
    float* kvp    = (float*)ws;                   // 16 MB (after xbf dead)
    float* ksp    = (float*)(ws + 16777216);      // 256 KB
    u16*   kvTbf  = (u16*)(ws + 17039360);        // 512 KB
    u16*   ksumbf = (u16*)(ws + 17563648);        // 8 KB

    convert_all<<<20480, 256, 0, stream>>>(x, Wq, Wk, Wv, Wo, xbf, wqkvbf, wobf);

    // fused QKV projection: [16384,1024] @ [3072,1024]^T, phi on q,k
    gemm8p<1><<<dim3(12, 64), 512, 131072, stream>>>(
        xbf, wqkvbf, bq, bk, bv, qbf, kbf, vbf, nullptr, 16384, 3072, 1024);

    kv_partial<<<dim3(64, 16), 256, 0, stream>>>(kbf, vbf, mask, kvp, ksp);
    kv_reduce<<<64, 256, 0, stream>>>(kvp, ksp, kvTbf, ksumbf);

    attn_kernel<<<dim3(64, 16), 256, 0, stream>>>(qbf, kvTbf, ksumbf, attnbf);

    gemm8p<0><<<dim3(4, 64), 512, 131072, stream>>>(
        attnbf, wobf, bo, bo, bo, nullptr, nullptr, nullptr, out, 16384, 1024, 1024);
}